// Round 4
// baseline (84.757 us; speedup 1.0000x reference)
//
#include <hip/hip_runtime.h>
#include <hip/hip_bf16.h>
#include <cstdint>
#include <cstddef>

typedef __attribute__((ext_vector_type(8))) short bf16x8;
typedef __attribute__((ext_vector_type(4))) float f32x4;
typedef __attribute__((ext_vector_type(4))) unsigned int u32x4;

#define T_DIM 2048
#define C_DIM 1024
#define B_DIM 8
#define NEG_BIG (-3.0e38f)

__device__ __forceinline__ unsigned short f2bf(float f) {
  union { __hip_bfloat16 h; unsigned short u; } cv;
  cv.h = __float2bfloat16(f);
  return cv.u;
}
__device__ __forceinline__ f32x4 mfma16(bf16x8 a, bf16x8 b, f32x4 c) {
  return __builtin_amdgcn_mfma_f32_16x16x32_bf16(a, b, c, 0, 0, 0);
}
__device__ __forceinline__ void gload16(const void* g, void* l) {
  __builtin_amdgcn_global_load_lds(
      (const __attribute__((address_space(1))) unsigned int*)g,
      (__attribute__((address_space(3))) unsigned int*)l, 16, 0, 0);
}

// ---------------------------------------------------------------------------
// prep_w: W [1024][64] f32 -> Wimg: per k-tile 24 KB block laid out EXACTLY as
// the proj kernel's LDS wants it (XOR swizzle baked in):
//   byte(kt,mtx,n,k) = kt*24576 + mtx*8192 + n*128 + ((k*2) ^ ((n&7)<<4))
// Wq scaled by 1/8. grid 48 = 3 matrices x 16 k-tiles.
// ---------------------------------------------------------------------------
__global__ __launch_bounds__(256) void prep_w(
    const float* __restrict__ Wq, const float* __restrict__ Wk,
    const float* __restrict__ Wv, char* __restrict__ Wimg)
{
  const int mtx = blockIdx.x >> 4;
  const int kt  = blockIdx.x & 15;
  const int k0  = kt * 64;
  const float* W = (mtx == 0) ? Wq : ((mtx == 1) ? Wk : Wv);
  const float scale = (mtx == 0) ? 0.125f : 1.0f;
  __shared__ float Ws[64][65];
  const int t = threadIdx.x;
#pragma unroll
  for (int j = 0; j < 4; ++j) {
    int r = (t >> 4) + 16 * j;          // k-local
    int c = (t & 15) * 4;               // n
    union { float4 f4; float f[4]; } uv;
    uv.f4 = *(const float4*)&W[(size_t)(k0 + r) * 64 + c];
#pragma unroll
    for (int jj = 0; jj < 4; ++jj) Ws[c + jj][r] = uv.f[jj] * scale;
  }
  __syncthreads();
  char* base = Wimg + (size_t)kt * 24576 + (size_t)mtx * 8192;
#pragma unroll
  for (int q = 0; q < 2; ++q) {
    int g_ = t + 256 * q;               // 0..511 granules of 16 B
    int n  = g_ >> 3;
    int k8 = (g_ & 7) * 8;
    union { unsigned short u[8]; u32x4 v; } pk;
#pragma unroll
    for (int jj = 0; jj < 8; ++jj) pk.u[jj] = f2bf(Ws[n][k8 + jj]);
    *(u32x4*)(base + n * 128 + ((k8 * 2) ^ ((n & 7) << 4))) = pk.v;
  }
}

// ---------------------------------------------------------------------------
// qkv_proj_mfma: [16384 x 1024] x [1024 x 192] -> Qb/Kb bf16, V transposed
// into VTb. X path is DIRECT global->reg->A-fragment (no LDS, no barrier);
// W path is linear global_load_lds from the pre-swizzled Wimg, double-buffered.
// grid 512 x 32 rows; 4 waves n-split (3 n-tiles each), both m-tiles.
// ---------------------------------------------------------------------------
__global__ __launch_bounds__(256) void qkv_proj_mfma(
    const float* __restrict__ x, const char* __restrict__ Wimg,
    const float* __restrict__ bq, const float* __restrict__ bk, const float* __restrict__ bv,
    unsigned short* __restrict__ Qb, unsigned short* __restrict__ Kb,
    unsigned short* __restrict__ VTb)
{
  __shared__ __align__(16) char Wsb[2][3 * 64 * 128];   // 24 KB each
  __shared__ __align__(16) unsigned short VTs[64 * 48]; // V-transpose tile

  const int tid = threadIdx.x;
  const int wv = tid >> 6, lane = tid & 63, g = lane >> 4, ln15 = lane & 15;
  const size_t m0 = (size_t)blockIdx.x * 32;

  f32x4 acc[2][3];
#pragma unroll
  for (int mt = 0; mt < 2; ++mt)
#pragma unroll
    for (int j = 0; j < 3; ++j) acc[mt][j] = (f32x4){0.f, 0.f, 0.f, 0.f};

  float4 xA[2][2][2], xB[2][2][2];   // [mt][kc][half] named double-buffer

  auto loadX = [&](float4 (&xr)[2][2][2], int kt) {
#pragma unroll
    for (int mt = 0; mt < 2; ++mt)
#pragma unroll
      for (int kc = 0; kc < 2; ++kc) {
        const float* p = &x[(m0 + mt * 16 + ln15) * C_DIM + kt * 64 + kc * 32 + g * 8];
        xr[mt][kc][0] = *(const float4*)p;
        xr[mt][kc][1] = *(const float4*)(p + 4);
      }
  };
  auto stageW = [&](int nb, int kt) {
    const char* src = Wimg + (size_t)kt * 24576;
    char* lb = Wsb[nb];
#pragma unroll
    for (int q = 0; q < 6; ++q) {
      int lin = (wv * 6 + q) * 1024 + lane * 16;
      gload16(src + lin, lb + lin);
    }
  };
  auto compute = [&](const float4 (&xr)[2][2][2], const char* wb) {
    bf16x8 a[2][2];
#pragma unroll
    for (int mt = 0; mt < 2; ++mt)
#pragma unroll
      for (int kc = 0; kc < 2; ++kc) {
        union { unsigned short u[8]; bf16x8 v; } pk;
        const float* f0 = (const float*)&xr[mt][kc][0];
        const float* f1 = (const float*)&xr[mt][kc][1];
#pragma unroll
        for (int jj = 0; jj < 4; ++jj) { pk.u[jj] = f2bf(f0[jj]); pk.u[4 + jj] = f2bf(f1[jj]); }
        a[mt][kc] = pk.v;
      }
#pragma unroll
    for (int kc = 0; kc < 2; ++kc)
#pragma unroll
      for (int j = 0; j < 3; ++j) {
        int ntg = wv * 3 + j;
        int mtx = ntg >> 2, nc = (ntg & 3) * 16;
        int wrow = nc + ln15;
        bf16x8 bb = *(const bf16x8*)(wb + mtx * 8192 + wrow * 128 + ((kc * 64 + g * 16) ^ ((wrow & 7) << 4)));
#pragma unroll
        for (int mt = 0; mt < 2; ++mt) acc[mt][j] = mfma16(a[mt][kc], bb, acc[mt][j]);
      }
  };

  loadX(xA, 0);
  stageW(0, 0);
  __syncthreads();                       // drain: W0 + xA resident

  for (int kt = 0; kt < 16; kt += 2) {
    loadX(xB, kt + 1);                   // prefetch next (regs)
    stageW(1, kt + 1);                   // prefetch next (LDS buf 1)
    compute(xA, Wsb[0]);
    __syncthreads();                     // drain: W1 + xB resident; Wsb[0] free
    if (kt + 2 < 16) { loadX(xA, kt + 2); stageW(0, kt + 2); }
    compute(xB, Wsb[1]);
    __syncthreads();                     // drain: W0' + xA' resident; Wsb[1] free
  }

  // epilogue: Q/K direct; V -> LDS transpose tile -> coalesced VTb
#pragma unroll
  for (int j = 0; j < 3; ++j) {
    int ntg = wv * 3 + j;
    int mtx = ntg >> 2, nc = (ntg & 3) * 16;
    if (mtx < 2) {
      const float* bias = (mtx == 0) ? bq : bk;
      unsigned short* Out = (mtx == 0) ? Qb : Kb;
      float bvv = bias[nc + ln15] * ((mtx == 0) ? 0.125f : 1.0f);
#pragma unroll
      for (int mt = 0; mt < 2; ++mt)
#pragma unroll
        for (int i = 0; i < 4; ++i)
          Out[(m0 + mt * 16 + 4 * g + i) * 64 + nc + ln15] = f2bf(acc[mt][j][i] + bvv);
    } else {
      float bvv = bv[nc + ln15];
#pragma unroll
      for (int mt = 0; mt < 2; ++mt)
#pragma unroll
        for (int i = 0; i < 4; ++i)
          VTs[(nc + ln15) * 48 + mt * 16 + 4 * g + i] = f2bf(acc[mt][j][i] + bvv);
    }
  }
  __syncthreads();
  {
    int d = tid >> 2, toff = (tid & 3) * 8;
    u32x4 v = *(const u32x4*)((const char*)VTs + d * 96 + toff * 2);
    size_t b = m0 >> 11, tloc = m0 & 2047;
    *(u32x4*)&VTb[(b * 64 + d) * T_DIM + tloc + toff] = v;
  }
}

// ---------------------------------------------------------------------------
// attn_mfma: flash attention, bf16 MFMA, 2-phase dbuf via global_load_lds.
// grid 512 = 64 q-tiles (32 rows) x 8 batches, balance-paired order.
// 4 waves: (q-row half) x (kv col half); halves merged via LDS at the end.
// (unchanged from round 3)
// ---------------------------------------------------------------------------
__global__ __launch_bounds__(256) void attn_mfma(
    const unsigned short* __restrict__ Qb,   // [B*T][64] (pre-scaled 1/8)
    const unsigned short* __restrict__ Kb,   // [B*T][64]
    const unsigned short* __restrict__ VTb,  // [B][64][T]
    float* __restrict__ out)
{
  __shared__ __align__(16) short Ksd[2][128 * 64];
  __shared__ __align__(16) short VTsd[2][64 * 128];
  __shared__ __align__(16) short Qs[32 * 64];
  __shared__ __align__(16) short Ps[4 * 16 * 64];
  __shared__ float ml2[2][16][2];

  const int tid  = threadIdx.x;
  const int wv   = tid >> 6;
  const int lane = tid & 63;
  const int g    = lane >> 4;
  const int ln15 = lane & 15;

  const int bx = blockIdx.x;
  const int qt = (bx < 256) ? (63 - (bx >> 3)) : ((bx - 256) >> 3);
  const int b  = bx & 7;
  const int r0 = qt * 32;
  const int half = wv & 1;
  const int ch   = wv >> 1;
  const int rmax = r0 + 31;
  const int NIT  = ((r0 + 31) >> 7) + 1;

  const char* Qg   = (const char*)(Qb + ((size_t)b * T_DIM + r0) * 64);
  const char* Kgb  = (const char*)(Kb + (size_t)b * T_DIM * 64);
  const char* VTgb = (const char*)(VTb + (size_t)b * 64 * T_DIM);

  auto stageKV = [&](int nb, int it) {
    const int s0 = it * 128;
    const char* kb2 = Kgb + (size_t)s0 * 128;
    char* kl = (char*)Ksd[nb];
#pragma unroll
    for (int q = 0; q < 4; ++q) {
      int lin = (wv * 4 + q) * 1024 + lane * 16;
      int row = lin >> 7, bo = lin & 127;
      gload16(kb2 + row * 128 + (bo ^ ((row & 7) << 4)), kl + lin);
    }
    const char* vb2 = VTgb + (size_t)s0 * 2;
    char* vl = (char*)VTsd[nb];
#pragma unroll
    for (int q = 0; q < 4; ++q) {
      int lin = (wv * 4 + q) * 1024 + lane * 16;
      int d = lin >> 8, bo = lin & 255;
      gload16(vb2 + (size_t)d * (T_DIM * 2) + (bo ^ ((d & 7) << 4)), vl + lin);
    }
  };

  {
    int lin = wv * 1024 + lane * 16;
    int row = lin >> 7, bo = lin & 127;
    gload16(Qg + row * 128 + (bo ^ ((row & 7) << 4)), (char*)Qs + lin);
  }
  stageKV(0, 0);
  __syncthreads();

  bf16x8 qa[2];
  {
    int qrow = 16 * half + ln15;
#pragma unroll
    for (int kc = 0; kc < 2; ++kc)
      qa[kc] = *(const bf16x8*)((const char*)Qs + qrow * 128 + ((kc * 64 + g * 16) ^ ((qrow & 7) << 4)));
  }

  f32x4 accv[4];
#pragma unroll
  for (int nt = 0; nt < 4; ++nt) accv[nt] = (f32x4){0.f, 0.f, 0.f, 0.f};
  float m_[4], l_[4];
#pragma unroll
  for (int i = 0; i < 4; ++i) { m_[i] = NEG_BIG; l_[i] = 0.f; }

  for (int it = 0; it < NIT; ++it) {
    const int cur = it & 1;
    if (it + 1 < NIT) stageKV(cur ^ 1, it + 1);

    const int s0  = it * 128;
    const int s0w = s0 + ch * 64;
    if (s0w <= rmax) {
      f32x4 sfr[4];
      __builtin_amdgcn_s_setprio(1);
#pragma unroll
      for (int nt = 0; nt < 4; ++nt) {
        f32x4 a = (f32x4){0.f, 0.f, 0.f, 0.f};
#pragma unroll
        for (int kc = 0; kc < 2; ++kc) {
          int krow = ch * 64 + nt * 16 + ln15;
          bf16x8 kb = *(const bf16x8*)((const char*)Ksd[cur] + krow * 128 + ((kc * 64 + g * 16) ^ ((krow & 7) << 4)));
          a = mfma16(qa[kc], kb, a);
        }
        sfr[nt] = a;
      }
      __builtin_amdgcn_s_setprio(0);
      if (s0w + 63 > r0 + 16 * half) {
#pragma unroll
        for (int nt = 0; nt < 4; ++nt) {
          int colg = s0w + nt * 16 + ln15;
#pragma unroll
          for (int i = 0; i < 4; ++i) {
            int rowg = r0 + 16 * half + 4 * g + i;
            if (colg > rowg) sfr[nt][i] = NEG_BIG;
          }
        }
      }
      float mx[4], corr[4];
#pragma unroll
      for (int i = 0; i < 4; ++i)
        mx[i] = fmaxf(fmaxf(sfr[0][i], sfr[1][i]), fmaxf(sfr[2][i], sfr[3][i]));
#pragma unroll
      for (int i = 0; i < 4; ++i) {
#pragma unroll
        for (int off = 1; off < 16; off <<= 1)
          mx[i] = fmaxf(mx[i], __shfl_xor(mx[i], off));
        float mn = fmaxf(m_[i], mx[i]);
        corr[i] = __expf(m_[i] - mn);
        m_[i] = mn;
      }
#pragma unroll
      for (int nt = 0; nt < 4; ++nt)
#pragma unroll
        for (int i = 0; i < 4; ++i)
          sfr[nt][i] = __expf(sfr[nt][i] - m_[i]);
#pragma unroll
      for (int i = 0; i < 4; ++i) {
        float ps = sfr[0][i] + sfr[1][i] + sfr[2][i] + sfr[3][i];
#pragma unroll
        for (int off = 1; off < 16; off <<= 1)
          ps += __shfl_xor(ps, off);
        l_[i] = l_[i] * corr[i] + ps;
      }
#pragma unroll
      for (int nt = 0; nt < 4; ++nt)
#pragma unroll
        for (int i = 0; i < 4; ++i)
          accv[nt][i] *= corr[i];
#pragma unroll
      for (int nt = 0; nt < 4; ++nt)
#pragma unroll
        for (int i = 0; i < 4; ++i) {
          int r_ = 4 * g + i;
          int cbo = (nt * 16 + ln15) * 2;
          *(unsigned short*)((char*)Ps + wv * 2048 + r_ * 128 + (cbo ^ ((r_ & 7) << 4))) = f2bf(sfr[nt][i]);
        }
      __builtin_amdgcn_s_setprio(1);
#pragma unroll
      for (int kc = 0; kc < 2; ++kc) {
        bf16x8 pa = *(const bf16x8*)((const char*)Ps + wv * 2048 + ln15 * 128 + ((kc * 64 + g * 16) ^ ((ln15 & 7) << 4)));
#pragma unroll
        for (int nt = 0; nt < 4; ++nt) {
          int vrow = nt * 16 + ln15;
          bf16x8 vb = *(const bf16x8*)((const char*)VTsd[cur] + vrow * 256 + ((ch * 128 + kc * 64 + g * 16) ^ ((vrow & 7) << 4)));
          accv[nt] = mfma16(pa, vb, accv[nt]);
        }
      }
      __builtin_amdgcn_s_setprio(0);
    }
    __syncthreads();
  }

  float* Z2 = (float*)Ksd[0];
  if (ch == 1) {
#pragma unroll
    for (int nt = 0; nt < 4; ++nt)
#pragma unroll
      for (int i = 0; i < 4; ++i)
        Z2[half * 1024 + (4 * g + i) * 64 + nt * 16 + ln15] = accv[nt][i];
    if (ln15 == 0) {
#pragma unroll
      for (int i = 0; i < 4; ++i) {
        ml2[half][4 * g + i][0] = m_[i];
        ml2[half][4 * g + i][1] = l_[i];
      }
    }
  }
  __syncthreads();
  if (ch == 0) {
    float c1[4], c2[4];
#pragma unroll
    for (int i = 0; i < 4; ++i) {
      float m2 = ml2[half][4 * g + i][0];
      float l2 = ml2[half][4 * g + i][1];
      float mm = fmaxf(m_[i], m2);
      float e1 = __expf(m_[i] - mm), e2 = __expf(m2 - mm);
      float inv = 1.0f / (l_[i] * e1 + l2 * e2);
      c1[i] = e1 * inv; c2[i] = e2 * inv;
    }
    float* ob = out + ((size_t)b * T_DIM + r0 + 16 * half) * 64;
#pragma unroll
    for (int nt = 0; nt < 4; ++nt)
#pragma unroll
      for (int i = 0; i < 4; ++i) {
        float z2 = Z2[half * 1024 + (4 * g + i) * 64 + nt * 16 + ln15];
        ob[(size_t)(4 * g + i) * 64 + nt * 16 + ln15] = accv[nt][i] * c1[i] + z2 * c2[i];
      }
  }
}

// ---------------------------------------------------------------------------
extern "C" void kernel_launch(void* const* d_in, const int* in_sizes, int n_in,
                              void* d_out, int out_size, void* d_ws, size_t ws_size,
                              hipStream_t stream)
{
  const float* x  = (const float*)d_in[0];
  const float* Wq = (const float*)d_in[1];
  const float* bq = (const float*)d_in[2];
  const float* Wk = (const float*)d_in[3];
  const float* bk = (const float*)d_in[4];
  const float* Wv = (const float*)d_in[5];
  const float* bv = (const float*)d_in[6];
  float* out = (float*)d_out;

  char* ws = (char*)d_ws;
  char*           Wimg = ws;                                        // 384 KB
  unsigned short* Qb  = (unsigned short*)(ws + (1u << 19));         // 2 MB
  unsigned short* Kb  = (unsigned short*)(ws + (1u << 19) + (1u << 21));
  unsigned short* VTb = (unsigned short*)(ws + (1u << 19) + (2u << 21));

  prep_w<<<48, 256, 0, stream>>>(Wq, Wk, Wv, Wimg);
  qkv_proj_mfma<<<512, 256, 0, stream>>>(x, Wimg, bq, bk, bv, Qb, Kb, VTb);
  attn_mfma<<<512, 256, 0, stream>>>(Qb, Kb, VTb, out);
}

// Round 5
// 63.738 us; speedup vs baseline: 1.3298x; 1.3298x over previous
//
#include <hip/hip_runtime.h>
#include <hip/hip_bf16.h>
#include <cstdint>
#include <cstddef>

typedef __attribute__((ext_vector_type(8))) short bf16x8;
typedef __attribute__((ext_vector_type(4))) float f32x4;
typedef __attribute__((ext_vector_type(4))) unsigned int u32x4;

#define T_DIM 2048
#define C_DIM 1024
#define B_DIM 8
#define NEG_BIG (-3.0e38f)

__device__ __forceinline__ unsigned short f2bf(float f) {
  union { __hip_bfloat16 h; unsigned short u; } cv;
  cv.h = __float2bfloat16(f);
  return cv.u;
}
__device__ __forceinline__ f32x4 mfma16(bf16x8 a, bf16x8 b, f32x4 c) {
  return __builtin_amdgcn_mfma_f32_16x16x32_bf16(a, b, c, 0, 0, 0);
}
__device__ __forceinline__ void gload16(const void* g, void* l) {
  __builtin_amdgcn_global_load_lds(
      (const __attribute__((address_space(1))) unsigned int*)g,
      (__attribute__((address_space(3))) unsigned int*)l, 16, 0, 0);
}

// ---------------------------------------------------------------------------
// prep_w: W [1024][64] f32 -> Wt [3][64][1024] bf16 (transposed; Wq scaled 1/8)
// (round-2 version)
// ---------------------------------------------------------------------------
__global__ __launch_bounds__(256) void prep_w(
    const float* __restrict__ Wq, const float* __restrict__ Wk,
    const float* __restrict__ Wv, unsigned short* __restrict__ Wt)
{
  const int mtx = blockIdx.x >> 4;
  const int k0  = (blockIdx.x & 15) * 64;
  const float* W = (mtx == 0) ? Wq : ((mtx == 1) ? Wk : Wv);
  const float scale = (mtx == 0) ? 0.125f : 1.0f;
  __shared__ float Ws[64][65];
  const int t = threadIdx.x;
#pragma unroll
  for (int j = 0; j < 4; ++j) {
    int r = (t >> 4) + 16 * j;
    int c = (t & 15) * 4;
    union { float4 f4; float f[4]; } uv;
    uv.f4 = *(const float4*)&W[(size_t)(k0 + r) * 64 + c];
#pragma unroll
    for (int jj = 0; jj < 4; ++jj) Ws[c + jj][r] = uv.f[jj] * scale;
  }
  __syncthreads();
#pragma unroll
  for (int q = 0; q < 2; ++q) {
    int g_ = t + 256 * q;
    int d  = g_ >> 3;
    int ko = (g_ & 7) * 8;
    union { unsigned short u[8]; u32x4 v; } pk;
#pragma unroll
    for (int jj = 0; jj < 8; ++jj) pk.u[jj] = f2bf(Ws[d][ko + jj]);
    *(u32x4*)&Wt[((size_t)mtx * 64 + d) * C_DIM + k0 + ko] = pk.v;
  }
}

// ---------------------------------------------------------------------------
// qkv_proj_mfma: round-2 structure VERBATIM (64 rows/block, 256 blocks,
// single-buffered LDS, stage -> barrier -> compute -> barrier), plus the
// fused V-transpose epilogue from round 4 (V -> LDS tile -> VTb coalesced).
// ---------------------------------------------------------------------------
__global__ __launch_bounds__(256) void qkv_proj_mfma(
    const float* __restrict__ x,
    const unsigned short* __restrict__ Wt,
    const float* __restrict__ bq, const float* __restrict__ bk, const float* __restrict__ bv,
    unsigned short* __restrict__ Qb, unsigned short* __restrict__ Kb,
    unsigned short* __restrict__ VTb)
{
  __shared__ __align__(16) short Xs[64 * 64];         // swizzled, stride 128B
  __shared__ __align__(16) short Ws[3 * 64 * 64];     // swizzled
  __shared__ __align__(16) unsigned short VTs[64 * 72]; // V-transpose tile

  const int tid = threadIdx.x;
  const int wv = tid >> 6, lane = tid & 63, g = lane >> 4, ln15 = lane & 15;
  const size_t m0 = (size_t)blockIdx.x * 64;

  f32x4 acc[4][3];
#pragma unroll
  for (int mt = 0; mt < 4; ++mt)
#pragma unroll
    for (int j = 0; j < 3; ++j) acc[mt][j] = (f32x4){0.f, 0.f, 0.f, 0.f};

  for (int kt = 0; kt < 16; ++kt) {
    __syncthreads();
    // stage X: 64x64 f32 -> bf16, coalesced float4 reads
#pragma unroll
    for (int q = 0; q < 4; ++q) {
      int g_ = tid + 256 * q;           // 0..1023 float4 granules
      int r = g_ >> 4, c4 = (g_ & 15) * 4;
      union { float4 f4; float f[4]; } uv;
      uv.f4 = *(const float4*)&x[(m0 + r) * C_DIM + kt * 64 + c4];
      union { unsigned short u[4]; unsigned long long ll; } pk;
#pragma unroll
      for (int jj = 0; jj < 4; ++jj) pk.u[jj] = f2bf(uv.f[jj]);
      *(unsigned long long*)((char*)Xs + r * 128 + ((c4 * 2) ^ ((r & 7) << 4))) = pk.ll;
    }
    // stage W tiles (bf16, 16B granules)
#pragma unroll
    for (int mt = 0; mt < 3; ++mt)
#pragma unroll
      for (int q = 0; q < 2; ++q) {
        int g_ = tid + 256 * q;
        int d = g_ >> 3, ko = (g_ & 7) * 8;
        u32x4 v = *(const u32x4*)&Wt[((size_t)mt * 64 + d) * C_DIM + kt * 64 + ko];
        *(u32x4*)((char*)Ws + mt * 8192 + d * 128 + ((ko * 2) ^ ((d & 7) << 4))) = v;
      }
    __syncthreads();
#pragma unroll
    for (int kc = 0; kc < 2; ++kc) {
      bf16x8 a[4];
#pragma unroll
      for (int mt = 0; mt < 4; ++mt) {
        int xr = mt * 16 + ln15;
        a[mt] = *(const bf16x8*)((const char*)Xs + xr * 128 + ((kc * 64 + g * 16) ^ ((xr & 7) << 4)));
      }
#pragma unroll
      for (int j = 0; j < 3; ++j) {
        int ntg = wv * 3 + j;
        int mtx = ntg >> 2, nc = (ntg & 3) * 16;
        int wrow = nc + ln15;
        bf16x8 bb = *(const bf16x8*)((const char*)Ws + mtx * 8192 + wrow * 128 + ((kc * 64 + g * 16) ^ ((wrow & 7) << 4)));
#pragma unroll
        for (int mt = 0; mt < 4; ++mt)
          acc[mt][j] = mfma16(a[mt], bb, acc[mt][j]);
      }
    }
  }

  // epilogue: Q/K direct; V -> LDS transpose tile -> coalesced VTb
  __syncthreads();
#pragma unroll
  for (int j = 0; j < 3; ++j) {
    int ntg = wv * 3 + j;
    int mtx = ntg >> 2, nc = (ntg & 3) * 16;
    if (mtx < 2) {
      const float* bias = (mtx == 0) ? bq : bk;
      unsigned short* Out = (mtx == 0) ? Qb : Kb;
      float bvv = bias[nc + ln15] * ((mtx == 0) ? 0.125f : 1.0f);
#pragma unroll
      for (int mt = 0; mt < 4; ++mt)
#pragma unroll
        for (int i = 0; i < 4; ++i)
          Out[(m0 + mt * 16 + 4 * g + i) * 64 + nc + ln15] = f2bf(acc[mt][j][i] + bvv);
    } else {
      float bvv = bv[nc + ln15];
#pragma unroll
      for (int mt = 0; mt < 4; ++mt)
#pragma unroll
        for (int i = 0; i < 4; ++i)
          VTs[(nc + ln15) * 72 + mt * 16 + 4 * g + i] = f2bf(acc[mt][j][i] + bvv);
    }
  }
  __syncthreads();
  {
    int d = tid >> 2, t8 = (tid & 3) * 16;   // 64 d-rows x 64 t-cols
    u32x4 v0 = *(const u32x4*)&VTs[d * 72 + t8];
    u32x4 v1 = *(const u32x4*)&VTs[d * 72 + t8 + 8];
    size_t b = m0 >> 11, tloc = m0 & 2047;
    *(u32x4*)&VTb[(b * 64 + d) * T_DIM + tloc + t8] = v0;
    *(u32x4*)&VTb[(b * 64 + d) * T_DIM + tloc + t8 + 8] = v1;
  }
}

// ---------------------------------------------------------------------------
// attn_mfma: unchanged from round 4 (est. ~18-20 us).
// ---------------------------------------------------------------------------
__global__ __launch_bounds__(256) void attn_mfma(
    const unsigned short* __restrict__ Qb,   // [B*T][64] (pre-scaled 1/8)
    const unsigned short* __restrict__ Kb,   // [B*T][64]
    const unsigned short* __restrict__ VTb,  // [B][64][T]
    float* __restrict__ out)
{
  __shared__ __align__(16) short Ksd[2][128 * 64];
  __shared__ __align__(16) short VTsd[2][64 * 128];
  __shared__ __align__(16) short Qs[32 * 64];
  __shared__ __align__(16) short Ps[4 * 16 * 64];
  __shared__ float ml2[2][16][2];

  const int tid  = threadIdx.x;
  const int wv   = tid >> 6;
  const int lane = tid & 63;
  const int g    = lane >> 4;
  const int ln15 = lane & 15;

  const int bx = blockIdx.x;
  const int qt = (bx < 256) ? (63 - (bx >> 3)) : ((bx - 256) >> 3);
  const int b  = bx & 7;
  const int r0 = qt * 32;
  const int half = wv & 1;
  const int ch   = wv >> 1;
  const int rmax = r0 + 31;
  const int NIT  = ((r0 + 31) >> 7) + 1;

  const char* Qg   = (const char*)(Qb + ((size_t)b * T_DIM + r0) * 64);
  const char* Kgb  = (const char*)(Kb + (size_t)b * T_DIM * 64);
  const char* VTgb = (const char*)(VTb + (size_t)b * 64 * T_DIM);

  auto stageKV = [&](int nb, int it) {
    const int s0 = it * 128;
    const char* kb2 = Kgb + (size_t)s0 * 128;
    char* kl = (char*)Ksd[nb];
#pragma unroll
    for (int q = 0; q < 4; ++q) {
      int lin = (wv * 4 + q) * 1024 + lane * 16;
      int row = lin >> 7, bo = lin & 127;
      gload16(kb2 + row * 128 + (bo ^ ((row & 7) << 4)), kl + lin);
    }
    const char* vb2 = VTgb + (size_t)s0 * 2;
    char* vl = (char*)VTsd[nb];
#pragma unroll
    for (int q = 0; q < 4; ++q) {
      int lin = (wv * 4 + q) * 1024 + lane * 16;
      int d = lin >> 8, bo = lin & 255;
      gload16(vb2 + (size_t)d * (T_DIM * 2) + (bo ^ ((d & 7) << 4)), vl + lin);
    }
  };

  {
    int lin = wv * 1024 + lane * 16;
    int row = lin >> 7, bo = lin & 127;
    gload16(Qg + row * 128 + (bo ^ ((row & 7) << 4)), (char*)Qs + lin);
  }
  stageKV(0, 0);
  __syncthreads();

  bf16x8 qa[2];
  {
    int qrow = 16 * half + ln15;
#pragma unroll
    for (int kc = 0; kc < 2; ++kc)
      qa[kc] = *(const bf16x8*)((const char*)Qs + qrow * 128 + ((kc * 64 + g * 16) ^ ((qrow & 7) << 4)));
  }

  f32x4 accv[4];
#pragma unroll
  for (int nt = 0; nt < 4; ++nt) accv[nt] = (f32x4){0.f, 0.f, 0.f, 0.f};
  float m_[4], l_[4];
#pragma unroll
  for (int i = 0; i < 4; ++i) { m_[i] = NEG_BIG; l_[i] = 0.f; }

  for (int it = 0; it < NIT; ++it) {
    const int cur = it & 1;
    if (it + 1 < NIT) stageKV(cur ^ 1, it + 1);

    const int s0  = it * 128;
    const int s0w = s0 + ch * 64;
    if (s0w <= rmax) {
      f32x4 sfr[4];
      __builtin_amdgcn_s_setprio(1);
#pragma unroll
      for (int nt = 0; nt < 4; ++nt) {
        f32x4 a = (f32x4){0.f, 0.f, 0.f, 0.f};
#pragma unroll
        for (int kc = 0; kc < 2; ++kc) {
          int krow = ch * 64 + nt * 16 + ln15;
          bf16x8 kb = *(const bf16x8*)((const char*)Ksd[cur] + krow * 128 + ((kc * 64 + g * 16) ^ ((krow & 7) << 4)));
          a = mfma16(qa[kc], kb, a);
        }
        sfr[nt] = a;
      }
      __builtin_amdgcn_s_setprio(0);
      if (s0w + 63 > r0 + 16 * half) {
#pragma unroll
        for (int nt = 0; nt < 4; ++nt) {
          int colg = s0w + nt * 16 + ln15;
#pragma unroll
          for (int i = 0; i < 4; ++i) {
            int rowg = r0 + 16 * half + 4 * g + i;
            if (colg > rowg) sfr[nt][i] = NEG_BIG;
          }
        }
      }
      float mx[4], corr[4];
#pragma unroll
      for (int i = 0; i < 4; ++i)
        mx[i] = fmaxf(fmaxf(sfr[0][i], sfr[1][i]), fmaxf(sfr[2][i], sfr[3][i]));
#pragma unroll
      for (int i = 0; i < 4; ++i) {
#pragma unroll
        for (int off = 1; off < 16; off <<= 1)
          mx[i] = fmaxf(mx[i], __shfl_xor(mx[i], off));
        float mn = fmaxf(m_[i], mx[i]);
        corr[i] = __expf(m_[i] - mn);
        m_[i] = mn;
      }
#pragma unroll
      for (int nt = 0; nt < 4; ++nt)
#pragma unroll
        for (int i = 0; i < 4; ++i)
          sfr[nt][i] = __expf(sfr[nt][i] - m_[i]);
#pragma unroll
      for (int i = 0; i < 4; ++i) {
        float ps = sfr[0][i] + sfr[1][i] + sfr[2][i] + sfr[3][i];
#pragma unroll
        for (int off = 1; off < 16; off <<= 1)
          ps += __shfl_xor(ps, off);
        l_[i] = l_[i] * corr[i] + ps;
      }
#pragma unroll
      for (int nt = 0; nt < 4; ++nt)
#pragma unroll
        for (int i = 0; i < 4; ++i)
          accv[nt][i] *= corr[i];
#pragma unroll
      for (int nt = 0; nt < 4; ++nt)
#pragma unroll
        for (int i = 0; i < 4; ++i) {
          int r_ = 4 * g + i;
          int cbo = (nt * 16 + ln15) * 2;
          *(unsigned short*)((char*)Ps + wv * 2048 + r_ * 128 + (cbo ^ ((r_ & 7) << 4))) = f2bf(sfr[nt][i]);
        }
      __builtin_amdgcn_s_setprio(1);
#pragma unroll
      for (int kc = 0; kc < 2; ++kc) {
        bf16x8 pa = *(const bf16x8*)((const char*)Ps + wv * 2048 + ln15 * 128 + ((kc * 64 + g * 16) ^ ((ln15 & 7) << 4)));
#pragma unroll
        for (int nt = 0; nt < 4; ++nt) {
          int vrow = nt * 16 + ln15;
          bf16x8 vb = *(const bf16x8*)((const char*)VTsd[cur] + vrow * 256 + ((ch * 128 + kc * 64 + g * 16) ^ ((vrow & 7) << 4)));
          accv[nt] = mfma16(pa, vb, accv[nt]);
        }
      }
      __builtin_amdgcn_s_setprio(0);
    }
    __syncthreads();
  }

  float* Z2 = (float*)Ksd[0];
  if (ch == 1) {
#pragma unroll
    for (int nt = 0; nt < 4; ++nt)
#pragma unroll
      for (int i = 0; i < 4; ++i)
        Z2[half * 1024 + (4 * g + i) * 64 + nt * 16 + ln15] = accv[nt][i];
    if (ln15 == 0) {
#pragma unroll
      for (int i = 0; i < 4; ++i) {
        ml2[half][4 * g + i][0] = m_[i];
        ml2[half][4 * g + i][1] = l_[i];
      }
    }
  }
  __syncthreads();
  if (ch == 0) {
    float c1[4], c2[4];
#pragma unroll
    for (int i = 0; i < 4; ++i) {
      float m2 = ml2[half][4 * g + i][0];
      float l2 = ml2[half][4 * g + i][1];
      float mm = fmaxf(m_[i], m2);
      float e1 = __expf(m_[i] - mm), e2 = __expf(m2 - mm);
      float inv = 1.0f / (l_[i] * e1 + l2 * e2);
      c1[i] = e1 * inv; c2[i] = e2 * inv;
    }
    float* ob = out + ((size_t)b * T_DIM + r0 + 16 * half) * 64;
#pragma unroll
    for (int nt = 0; nt < 4; ++nt)
#pragma unroll
      for (int i = 0; i < 4; ++i) {
        float z2 = Z2[half * 1024 + (4 * g + i) * 64 + nt * 16 + ln15];
        ob[(size_t)(4 * g + i) * 64 + nt * 16 + ln15] = accv[nt][i] * c1[i] + z2 * c2[i];
      }
  }
}

// ---------------------------------------------------------------------------
extern "C" void kernel_launch(void* const* d_in, const int* in_sizes, int n_in,
                              void* d_out, int out_size, void* d_ws, size_t ws_size,
                              hipStream_t stream)
{
  const float* x  = (const float*)d_in[0];
  const float* Wq = (const float*)d_in[1];
  const float* bq = (const float*)d_in[2];
  const float* Wk = (const float*)d_in[3];
  const float* bk = (const float*)d_in[4];
  const float* Wv = (const float*)d_in[5];
  const float* bv = (const float*)d_in[6];
  float* out = (float*)d_out;

  char* ws = (char*)d_ws;
  unsigned short* Wt  = (unsigned short*)(ws);                      // 384 KB
  unsigned short* Qb  = (unsigned short*)(ws + (1u << 19));         // 2 MB
  unsigned short* Kb  = (unsigned short*)(ws + (1u << 19) + (1u << 21));
  unsigned short* VTb = (unsigned short*)(ws + (1u << 19) + (2u << 21));

  prep_w<<<48, 256, 0, stream>>>(Wq, Wk, Wv, Wt);
  qkv_proj_mfma<<<256, 256, 0, stream>>>(x, Wt, bq, bk, bv, Qb, Kb, VTb);
  attn_mfma<<<512, 256, 0, stream>>>(Qb, Kb, VTb, out);
}